// Round 2
// baseline (2252.396 us; speedup 1.0000x reference)
//
#include <hip/hip_runtime.h>
#include <math.h>

// Problem constants (N,C,H,W) = (8,64,256,256)
constexpr int Nn    = 8;
constexpr int Cc    = 64;
constexpr int HWp   = 65536;          // H*W
constexpr int TPB   = 256;            // threads per block (4 waves)
constexpr int Pt    = 128;            // pixels per LDS tile
constexpr int CHUNK = 1024;           // pixels per block
constexpr int TILES = CHUNK / Pt;     // 8
constexpr int CHUNKS = HWp / CHUNK;   // 64

// ---------- helpers ----------
__device__ inline unsigned fkey(float f) {
  unsigned u = __float_as_uint(f);
  return (u & 0x80000000u) ? ~u : (u | 0x80000000u);  // order-preserving float->uint
}
__device__ inline float funkey(unsigned k) {
  return __uint_as_float((k & 0x80000000u) ? (k & 0x7fffffffu) : ~k);
}
__device__ inline float wmax(float v) {
#pragma unroll
  for (int m = 32; m; m >>= 1) v = fmaxf(v, __shfl_xor(v, m, 64));
  return v;
}
__device__ inline float wsum(float v) {
#pragma unroll
  for (int m = 32; m; m >>= 1) v += __shfl_xor(v, m, 64);
  return v;
}
__device__ inline void wsum4(float& a, float& b, float& c, float& d) {
#pragma unroll
  for (int m = 32; m; m >>= 1) {
    a += __shfl_xor(a, m, 64);
    b += __shfl_xor(b, m, 64);
    c += __shfl_xor(c, m, 64);
    d += __shfl_xor(d, m, 64);
  }
}
__device__ inline float silu_(float z) { return z / (1.f + __expf(-z)); }

// stage 64ch x 128px fp32 tile into LDS, layout lds[c*Pt + p], coalesced float4
__device__ inline void stage_tile(const float* __restrict__ xim, int px, float* lds) {
  const int t  = threadIdx.x;
  const int p4 = (t & 31) << 2;  // pixel*1 within tile, 4 at a time
  const int cb = t >> 5;         // 0..7
#pragma unroll
  for (int pass = 0; pass < 8; pass++) {
    const int c = pass * 8 + cb;
    const float4 f = *(const float4*)&xim[(size_t)c * HWp + px + p4];
    *(float4*)&lds[c * Pt + p4] = f;
  }
}

// ---------- k1: conv stats (per-channel max+sum over pixels) + key pre-softmax ----------
// lane owns output channel o=lane; weight row in 64 VGPRs; x tile in LDS.
__global__ __launch_bounds__(TPB, 4) void k1_stats(
    const float* __restrict__ xrgb, const float* __restrict__ xir,
    const float* __restrict__ conv_w, const float* __restrict__ conv_b,
    const float* __restrict__ key_w, const float* __restrict__ key_g,
    const float* __restrict__ key_b, const float* __restrict__ key_m,
    const float* __restrict__ key_v,
    float* __restrict__ kpre, unsigned* __restrict__ mxk,
    float* __restrict__ smo, unsigned* __restrict__ kmaxk)
{
  __shared__ __align__(16) float ltile[Cc * Pt];   // 32 KB
  __shared__ float redm[4][64];
  __shared__ float reds[4][64];
  const int side = blockIdx.z, n = blockIdx.y;
  const int sn = side * Nn + n;
  const float* xim = (side ? xir : xrgb) + (size_t)n * Cc * HWp;
  const int lane = threadIdx.x & 63, w = threadIdx.x >> 6;

  float wr[64];
#pragma unroll
  for (int c4 = 0; c4 < 16; c4++) {
    const float4 f = *(const float4*)&conv_w[lane * 64 + c4 * 4];
    wr[c4 * 4 + 0] = f.x; wr[c4 * 4 + 1] = f.y; wr[c4 * 4 + 2] = f.z; wr[c4 * 4 + 3] = f.w;
  }
  const float cb = conv_b[lane];
  const float ks = key_g[0] * rsqrtf(key_v[0] + 1e-5f);
  const float kb = key_b[0] - key_m[0] * ks;
  float mx = -1e30f, sms = 0.f, kml = -1e30f;
  float* kp = kpre + (size_t)sn * HWp;

  for (int tile = 0; tile < TILES; tile++) {
    const int px = blockIdx.x * CHUNK + tile * Pt;
    __syncthreads();
    stage_tile(xim, px, ltile);
    __syncthreads();
    // main conv: wave w covers pixels [w*32, w*32+32), 4 at a time
#pragma unroll 1
    for (int g = 0; g < 8; g++) {
      const float* lp = ltile + w * 32 + g * 4;
      float a0 = cb, a1 = cb, a2 = cb, a3 = cb;
#pragma unroll
      for (int c = 0; c < 64; c++) {
        const float4 xc = *(const float4*)&lp[c * Pt];  // wave-broadcast
        a0 = fmaf(wr[c], xc.x, a0);
        a1 = fmaf(wr[c], xc.y, a1);
        a2 = fmaf(wr[c], xc.z, a2);
        a3 = fmaf(wr[c], xc.w, a3);
      }
      mx = fmaxf(mx, fmaxf(fmaxf(a0, a1), fmaxf(a2, a3)));
      sms += (a0 + a1) + (a2 + a3);
    }
    // key conv for this wave's 32 pixels (lanes 32..63 duplicate 0..31; broadcast reads)
    const int kpx = w * 32 + (lane & 31);
    float kd = 0.f;
#pragma unroll
    for (int c = 0; c < 64; c++) kd += key_w[c] * ltile[c * Pt + kpx];
    const float ka = silu_(ks * kd + kb);
    kml = fmaxf(kml, ka);
    if (lane < 32) kp[px + kpx] = ka;
  }
  // block-level combine (same o across the 4 waves), then one atomic per o
  redm[w][lane] = mx;
  reds[w][lane] = sms;
  __syncthreads();
  if (w == 0) {
    const float m = fmaxf(fmaxf(redm[0][lane], redm[1][lane]), fmaxf(redm[2][lane], redm[3][lane]));
    const float s = (reds[0][lane] + reds[1][lane]) + (reds[2][lane] + reds[3][lane]);
    atomicMax(&mxk[sn * 64 + lane], fkey(m));
    atomicAdd(&smo[sn * 64 + lane], s);
  }
  kml = wmax(kml);
  if (lane == 0) atomicMax(&kmaxk[sn], fkey(kml));
}

// ---------- k2: key softmax denominator ----------
__global__ void k2_ksum(const float* __restrict__ kpre,
                        const unsigned* __restrict__ kmaxk,
                        float* __restrict__ ksum)
{
  const int sn = blockIdx.x;  // 0..15
  const float kmax = funkey(kmaxk[sn]);
  const float* kp = kpre + (size_t)sn * HWp;
  const int lo = blockIdx.y * 8192, hi = lo + 8192;
  float s = 0.f;
  for (int e = lo + threadIdx.x; e < hi; e += TPB) s += __expf(kp[e] - kmax);
  s = wsum(s);
  __shared__ float red[4];
  const int w = threadIdx.x >> 6, lane = threadIdx.x & 63;
  if (lane == 0) red[w] = s;
  __syncthreads();
  if (threadIdx.x == 0) atomicAdd(&ksum[sn], red[0] + red[1] + red[2] + red[3]);
}

// ---------- k3: avg/max softmax over channels + val-BN constants ----------
__global__ void k3_fin(const float* __restrict__ smo, const unsigned* __restrict__ mxk,
                       const float* __restrict__ val_g, const float* __restrict__ val_b,
                       const float* __restrict__ val_m, const float* __restrict__ val_v,
                       float* __restrict__ avg, float* __restrict__ mxs,
                       float* __restrict__ vs_arr, float* __restrict__ vb_arr)
{
  const int sn = blockIdx.x, o = threadIdx.x;  // 64 threads = 1 wave
  if (sn == 0) {
    float s = val_g[o] * rsqrtf(val_v[o] + 1e-5f);
    vs_arr[o] = s;
    vb_arr[o] = val_b[o] - val_m[o] * s;
  }
  float lm = smo[sn * 64 + o] * (1.f / HWp);
  float M = wmax(lm);
  float E = __expf(lm - M);
  float S = wsum(E);
  avg[sn * 64 + o] = E / S;
  float mm = funkey(mxk[sn * 64 + o]);
  M = wmax(mm);
  E = __expf(mm - M);
  S = wsum(E);
  mxs[sn * 64 + o] = E / S;
}

// ---------- k4: val conv on-the-fly + fea/half contractions ----------
__global__ __launch_bounds__(TPB, 4) void k4_val(
    const float* __restrict__ xrgb, const float* __restrict__ xir,
    const float* __restrict__ val_w,
    const float* __restrict__ vs_arr, const float* __restrict__ vb_arr,
    const float* __restrict__ avg, const float* __restrict__ mxs,
    const float* __restrict__ kpre, const unsigned* __restrict__ kmaxk,
    const float* __restrict__ ksum,
    const float* __restrict__ half_w, const float* __restrict__ half_g,
    const float* __restrict__ half_b, const float* __restrict__ half_m,
    const float* __restrict__ half_v,
    float* __restrict__ halfb, float* __restrict__ fea)
{
  __shared__ __align__(16) float ltile[Cc * Pt];   // 32 KB
  __shared__ __align__(16) float lkw[Pt];
  __shared__ float redf[4][64];
  const int me = blockIdx.z, n = blockIdx.y;
  const int sn = me * Nn + n;
  // v comes from the OTHER side's features; stats/key/half/fea belong to `me`
  const float* xo = (me ? xrgb : xir) + (size_t)n * Cc * HWp;
  const int lane = threadIdx.x & 63, w = threadIdx.x >> 6;

  float wr[64];
#pragma unroll
  for (int c4 = 0; c4 < 16; c4++) {
    const float4 f = *(const float4*)&val_w[lane * 64 + c4 * 4];
    wr[c4 * 4 + 0] = f.x; wr[c4 * 4 + 1] = f.y; wr[c4 * 4 + 2] = f.z; wr[c4 * 4 + 3] = f.w;
  }
  const float vs = vs_arr[lane], vb = vb_arr[lane];
  const float hw0 = half_w[0], hw1 = half_w[1];
  const float cq = hw0 * avg[sn * 64 + lane] + hw1 * mxs[sn * 64 + lane];
  const float hs = half_g[0] * rsqrtf(half_v[0] + 1e-5f);
  const float hb = half_b[0] - half_m[0] * hs;
  const float kmax = funkey(kmaxk[sn]);
  const float kinv = 1.f / ksum[sn];
  const float* kpim = kpre + (size_t)sn * HWp;
  float* hp = halfb + (size_t)sn * HWp;
  float feap = 0.f;

  for (int tile = 0; tile < TILES; tile++) {
    const int px = blockIdx.x * CHUNK + tile * Pt;
    __syncthreads();
    stage_tile(xo, px, ltile);
    if (threadIdx.x < 32) {  // key softmax weights for this tile
      const float4 kf = *(const float4*)&kpim[px + threadIdx.x * 4];
      float4 e;
      e.x = __expf(kf.x - kmax) * kinv;
      e.y = __expf(kf.y - kmax) * kinv;
      e.z = __expf(kf.z - kmax) * kinv;
      e.w = __expf(kf.w - kmax) * kinv;
      *(float4*)&lkw[threadIdx.x * 4] = e;
    }
    __syncthreads();
#pragma unroll 1
    for (int g = 0; g < 8; g++) {
      const int pg = w * 32 + g * 4;
      const float* lp = ltile + pg;
      float a0 = 0.f, a1 = 0.f, a2 = 0.f, a3 = 0.f;
#pragma unroll
      for (int c = 0; c < 64; c++) {
        const float4 xc = *(const float4*)&lp[c * Pt];  // wave-broadcast
        a0 = fmaf(wr[c], xc.x, a0);
        a1 = fmaf(wr[c], xc.y, a1);
        a2 = fmaf(wr[c], xc.z, a2);
        a3 = fmaf(wr[c], xc.w, a3);
      }
      const float v0 = silu_(vs * a0 + vb);
      const float v1 = silu_(vs * a1 + vb);
      const float v2 = silu_(vs * a2 + vb);
      const float v3 = silu_(vs * a3 + vb);
      const float4 kw4 = *(const float4*)&lkw[pg];
      feap = fmaf(v0, kw4.x, fmaf(v1, kw4.y, fmaf(v2, kw4.z, fmaf(v3, kw4.w, feap))));
      float t0 = cq * v0, t1 = cq * v1, t2 = cq * v2, t3 = cq * v3;
      wsum4(t0, t1, t2, t3);  // hw0*avgm + hw1*maxm per pixel
      if (lane == 0) {
        float4 hv;
        hv.x = silu_(hs * t0 + hb);
        hv.y = silu_(hs * t1 + hb);
        hv.z = silu_(hs * t2 + hb);
        hv.w = silu_(hs * t3 + hb);
        *(float4*)&hp[px + pg] = hv;
      }
    }
  }
  redf[w][lane] = feap;
  __syncthreads();
  if (w == 0) {
    const float s = (redf[0][lane] + redf[1][lane]) + (redf[2][lane] + redf[3][lane]);
    atomicAdd(&fea[sn * 64 + lane], s);
  }
}

// ---------- k5: gate = sigmoid(LN(fea @ convb_w^T)) ----------
__global__ void k5_gate(const float* __restrict__ fea, const float* __restrict__ convb_w,
                        const float* __restrict__ ln_g, const float* __restrict__ ln_b,
                        float* __restrict__ gate)
{
  const int sn = blockIdx.x, o = threadIdx.x;  // 64 threads = 1 wave
  float z = 0.f;
#pragma unroll
  for (int c = 0; c < 64; c++) z += convb_w[o * 64 + c] * fea[sn * 64 + c];
  float mu = wsum(z) * (1.f / 64);
  float d = z - mu;
  float var = wsum(d * d) * (1.f / 64);
  float g = d * rsqrtf(var + 1e-5f) * ln_g[o] + ln_b[o];
  gate[sn * 64 + o] = 1.f / (1.f + __expf(-g));
}

// ---------- k6: out = gate*half + x (streaming, float4) ----------
__global__ __launch_bounds__(256) void k6_out(
    const float* __restrict__ xrgb, const float* __restrict__ xir,
    const float* __restrict__ gate, const float* __restrict__ halfb,
    float* __restrict__ out)
{
  const size_t t = (size_t)blockIdx.x * 256 + threadIdx.x;  // float4 index
  const int e4 = (int)(t & (HWp / 4 - 1));
  size_t r = t >> 14;
  const int c = (int)(r & 63); r >>= 6;
  const int n = (int)(r & 7);
  const int me = (int)(r >> 3);
  const float* x = me ? xir : xrgb;
  const float4 xv = ((const float4*)x)[(((size_t)n * 64 + c) << 14) + e4];
  const float g = gate[(me * 8 + n) * 64 + c];
  const float4 h = ((const float4*)halfb)[((size_t)(me * 8 + n) << 14) + e4];
  float4 ov;
  ov.x = g * h.x + xv.x;
  ov.y = g * h.y + xv.y;
  ov.z = g * h.z + xv.z;
  ov.w = g * h.w + xv.w;
  ((float4*)out)[t] = ov;
}

extern "C" void kernel_launch(void* const* d_in, const int* in_sizes, int n_in,
                              void* d_out, int out_size, void* d_ws, size_t ws_size,
                              hipStream_t stream)
{
  const float* xrgb   = (const float*)d_in[0];
  const float* xir    = (const float*)d_in[1];
  const float* conv_w = (const float*)d_in[2];
  const float* conv_b = (const float*)d_in[3];
  const float* key_w  = (const float*)d_in[4];
  const float* key_g  = (const float*)d_in[5];
  const float* key_b  = (const float*)d_in[6];
  const float* key_m  = (const float*)d_in[7];
  const float* key_v  = (const float*)d_in[8];
  const float* val_w  = (const float*)d_in[9];
  const float* val_g  = (const float*)d_in[10];
  const float* val_b  = (const float*)d_in[11];
  const float* val_m  = (const float*)d_in[12];
  const float* val_v  = (const float*)d_in[13];
  const float* convb_w= (const float*)d_in[14];
  const float* half_w = (const float*)d_in[15];
  const float* half_g = (const float*)d_in[16];
  const float* half_b = (const float*)d_in[17];
  const float* half_m = (const float*)d_in[18];
  const float* half_v = (const float*)d_in[19];
  const float* ln_g   = (const float*)d_in[20];
  const float* ln_b   = (const float*)d_in[21];

  // workspace layout (floats): ~8.4 MiB total
  float* ws      = (float*)d_ws;
  float* kpre    = ws;                    // [2][8][HW]
  float* halfb   = kpre + 2 * Nn * HWp;   // [2][8][HW]
  float* smo     = halfb + 2 * Nn * HWp;  // [2][8][64]
  unsigned* mxk  = (unsigned*)(smo + 1024);   // [2][8][64]
  unsigned* kmaxk= mxk + 1024;            // [2][8]
  float* ksum    = (float*)(kmaxk + 16);  // [2][8]
  float* fea     = ksum + 16;             // [2][8][64]
  float* avg     = fea + 1024;            // [2][8][64]
  float* mxs     = avg + 1024;            // [2][8][64]
  float* gate    = mxs + 1024;            // [2][8][64]
  float* vs_arr  = gate + 1024;           // [64]
  float* vb_arr  = vs_arr + 64;           // [64]

  // zero accumulators (smo, mxk, kmaxk, ksum, fea are contiguous)
  hipMemsetAsync(smo, 0, (size_t)(1024 + 1024 + 16 + 16 + 1024) * sizeof(float), stream);

  dim3 gHeavy(CHUNKS, Nn, 2);
  k1_stats<<<gHeavy, TPB, 0, stream>>>(xrgb, xir, conv_w, conv_b, key_w, key_g, key_b,
                                       key_m, key_v, kpre, mxk, smo, kmaxk);
  k2_ksum<<<dim3(16, 8), TPB, 0, stream>>>(kpre, kmaxk, ksum);
  k3_fin<<<16, 64, 0, stream>>>(smo, mxk, val_g, val_b, val_m, val_v, avg, mxs, vs_arr, vb_arr);
  k4_val<<<gHeavy, TPB, 0, stream>>>(xrgb, xir, val_w, vs_arr, vb_arr, avg, mxs, kpre,
                                     kmaxk, ksum, half_w, half_g, half_b, half_m, half_v,
                                     halfb, fea);
  k5_gate<<<16, 64, 0, stream>>>(fea, convb_w, ln_g, ln_b, gate);
  k6_out<<<(2 * Nn * Cc * HWp / 4) / 256, 256, 0, stream>>>(xrgb, xir, gate, halfb,
                                                            (float*)d_out);
}